// Round 4
// baseline (124.532 us; speedup 1.0000x reference)
//
#include <hip/hip_runtime.h>
#include <cstddef>

// B=8, Cin=32, D=16, H=W=32 -> ConvTranspose3d(32->64, k=3, s=2, p=1)
// -> mean over depth (D'=31) -> +bias -> softmax over C=64 -> tanh*2.
// Output (8, 64, 1, 63, 63) fp32.
//
// Depth-mean folds into weights: A0 = S - x[0], A1 = S, A2 = S - x[15]
// (S = sum_d x), m = cb + sum_kd Tconv2d(A_kd, w/31).
// Parity classes (oh&1, ow&1): taps/cin = 3 (EE), 6 (EO/OE), 12 (OO).
//
// Round-4 structure (anti-spill): one WAVE owns (b, oh, cp, ow-quarter).
//   lanes = couts, acc[8] pixels only. Weights streamed per-cin from L2
//   (12-48 B/lane, coalesced, shared by all waves of the class) -- NOT
//   register-resident. A-row 9-dword segments are wave-uniform s_loads.
//   Softmax = in-wave 64-lane butterfly. No LDS, no barriers, no cross-wave
//   reduce. Live VGPRs ~50-80 -> no scratch (rounds 1-3 all spilled:
//   WRITE_SIZE showed ~10 MB of scratch traffic, everything latency-bound).

namespace {
constexpr int PLANE  = 8 * 32 * 32 * 32;          // floats per A plane
constexpr int OFF_EE = 0;                          // T=3
constexpr int OFF_EO = 32 * 64 * 3;                // T=6
constexpr int OFF_OE = OFF_EO + 32 * 64 * 6;       // T=6
constexpr int OFF_OO = OFF_OE + 32 * 64 * 6;       // T=12
constexpr int OFF_CB = OFF_OO + 32 * 64 * 12;      // cb[64]
constexpr int OFF_A  = OFF_CB + 64;                // 3 planes follow
}

// ---------------- prep: weight transform (+bias) AND depth reduce ----------
extern "C" __global__ __launch_bounds__(256) void k_prep(
    const float* __restrict__ x, const float* __restrict__ w,
    const float* __restrict__ conv_bias, const float* __restrict__ bias,
    float* __restrict__ ws) {
  const int bid = blockIdx.x;
  const int tid = threadIdx.x;
  if (bid < 8) {
    int t = bid * 256 + tid;                       // cin*64+cout over 2048
    if (t < 64) ws[OFF_CB + t] = conv_bias[t] + bias[t];
    if (t >= 32 * 64) return;
    const float s = 1.0f / 31.0f;
    const float* src = w + t * 27;                 // (Cin, Cout, 3,3,3)
    float wv[27];
#pragma unroll
    for (int i = 0; i < 27; ++i) wv[i] = src[i] * s;
    float* dee = ws + OFF_EE + t * 3;
    float* deo = ws + OFF_EO + t * 6;
    float* doe = ws + OFF_OE + t * 6;
    float* doo = ws + OFF_OO + t * 12;
#pragma unroll
    for (int kd = 0; kd < 3; ++kd) {
      dee[kd]         = wv[kd * 9 + 4];            // (kh=1, kw=1)
      deo[kd * 2 + 0] = wv[kd * 9 + 3 + 0];        // (1,0) uses a[pix+1]
      deo[kd * 2 + 1] = wv[kd * 9 + 3 + 2];        // (1,2) uses a[pix]
      doe[kd * 2 + 0] = wv[kd * 9 + 0 + 1];        // (0,1) uses rowA=(oh+1)/2
      doe[kd * 2 + 1] = wv[kd * 9 + 6 + 1];        // (2,1) uses rowB=(oh-1)/2
      doo[kd * 4 + 0] = wv[kd * 9 + 0];            // (0,0) rowA, a[pix+1]
      doo[kd * 4 + 1] = wv[kd * 9 + 2];            // (0,2) rowA, a[pix]
      doo[kd * 4 + 2] = wv[kd * 9 + 6];            // (2,0) rowB, a[pix+1]
      doo[kd * 4 + 3] = wv[kd * 9 + 8];            // (2,2) rowB, a[pix]
    }
  } else {
    // depth reduce, d-split across lane halves: 131072 threads
    int t = (bid - 8) * 256 + tid;
    int g = t >> 6;
    int lane = t & 63;
    int dh = lane >> 5;
    int o = g * 32 + (lane & 31);                  // float4 output index
    int bc = o >> 8;
    int c4 = o & 255;
    const float4* xp = (const float4*)x + (size_t)bc * 4096 + c4;
    float4 vv[8];
#pragma unroll
    for (int j = 0; j < 8; ++j) vv[j] = xp[(dh * 8 + j) * 256];
    float sx = 0.f, sy = 0.f, sz = 0.f, sw = 0.f;
#pragma unroll
    for (int j = 0; j < 8; ++j) { sx += vv[j].x; sy += vv[j].y; sz += vv[j].z; sw += vv[j].w; }
    float fx = sx + __shfl_xor(sx, 32);
    float fy = sy + __shfl_xor(sy, 32);
    float fz = sz + __shfl_xor(sz, 32);
    float fw = sw + __shfl_xor(sw, 32);
    float4* Af = (float4*)(ws + OFF_A);
    if (dh == 0) {
      float4 a0; a0.x = fx - vv[0].x; a0.y = fy - vv[0].y; a0.z = fz - vv[0].z; a0.w = fw - vv[0].w;
      Af[o] = a0;                                   // A0 (drops d=0)
      float4 a1; a1.x = fx; a1.y = fy; a1.z = fz; a1.w = fw;
      Af[PLANE / 4 + o] = a1;                       // A1
    } else {
      float4 a2; a2.x = fx - vv[7].x; a2.y = fy - vv[7].y; a2.z = fz - vv[7].z; a2.w = fw - vv[7].w;
      Af[2 * (PLANE / 4) + o] = a2;                 // A2 (drops d=15)
    }
  }
}

// ---------------- main: one wave per (b, oh, cp, quarter) ------------------
template <int RP, int CP>
__device__ __forceinline__ void wave_body(const float* __restrict__ ws,
                                          float* __restrict__ out,
                                          int b, int oh, int q, int lane) {
  constexpr int T    = 3 * (RP + 1) * (CP + 1);
  constexpr int toff = RP ? (CP ? OFF_OO : OFF_OE) : (CP ? OFF_EO : OFF_EE);
  const int ihA = RP ? (oh + 1) >> 1 : oh >> 1;
  const int ihB = RP ? (oh - 1) >> 1 : 0;
  // p=7's "pix+1" index, clamped for the invalid (q==3, CP==1) tail pixel.
  const int e8  = (CP == 1 && q == 3) ? 7 : 8;      // uniform
  const int npx = (CP == 1 && q == 3) ? 7 : 8;      // valid pixel count

  const float* A  = ws + OFF_A;
  const float* wt = ws + toff;
  const int seg = q * 8;

  float acc[8];
#pragma unroll
  for (int p = 0; p < 8; ++p) acc[p] = 0.0f;

#pragma unroll 2
  for (int ci = 0; ci < 32; ++ci) {
    // per-lane weights for this cin: T contiguous dwords, lane-coalesced
    float wr[T];
    const float* wp = wt + (size_t)(ci * 64 + lane) * T;
#pragma unroll
    for (int tt = 0; tt < T; ++tt) wr[tt] = wp[tt];

    const int rowbase = (b * 32 + ci) * 32;
#pragma unroll
    for (int kd = 0; kd < 3; ++kd) {
      const float* arA = A + kd * PLANE + (rowbase + ihA) * 32 + seg;  // uniform
      const float* arB = A + kd * PLANE + (rowbase + ihB) * 32 + seg;
      if constexpr (RP == 0 && CP == 0) {
        const float w0 = wr[kd];
#pragma unroll
        for (int p = 0; p < 8; ++p) acc[p] = fmaf(arA[p], w0, acc[p]);
      } else if constexpr (RP == 0 && CP == 1) {
        const float w0 = wr[kd * 2 + 0];
        const float w2 = wr[kd * 2 + 1];
#pragma unroll
        for (int p = 0; p < 8; ++p) {
          const int ip1 = (p < 7) ? p + 1 : e8;
          acc[p] = fmaf(arA[ip1], w0, acc[p]);
          acc[p] = fmaf(arA[p],   w2, acc[p]);
        }
      } else if constexpr (RP == 1 && CP == 0) {
        const float wa = wr[kd * 2 + 0];
        const float wb = wr[kd * 2 + 1];
#pragma unroll
        for (int p = 0; p < 8; ++p) {
          acc[p] = fmaf(arA[p], wa, acc[p]);
          acc[p] = fmaf(arB[p], wb, acc[p]);
        }
      } else {
        const float w00 = wr[kd * 4 + 0];
        const float w02 = wr[kd * 4 + 1];
        const float w20 = wr[kd * 4 + 2];
        const float w22 = wr[kd * 4 + 3];
#pragma unroll
        for (int p = 0; p < 8; ++p) {
          const int ip1 = (p < 7) ? p + 1 : e8;
          acc[p] = fmaf(arA[ip1], w00, acc[p]);
          acc[p] = fmaf(arA[p],   w02, acc[p]);
          acc[p] = fmaf(arB[ip1], w20, acc[p]);
          acc[p] = fmaf(arB[p],   w22, acc[p]);
        }
      }
    }
  }

  // + per-cout bias, then in-wave softmax over lanes (8 interleaved chains)
  const float cbv = ws[OFF_CB + lane];
  float mx[8];
#pragma unroll
  for (int p = 0; p < 8; ++p) { acc[p] += cbv; mx[p] = acc[p]; }
#pragma unroll
  for (int s = 1; s < 64; s <<= 1) {
#pragma unroll
    for (int p = 0; p < 8; ++p) mx[p] = fmaxf(mx[p], __shfl_xor(mx[p], s));
  }
  float sm[8];
#pragma unroll
  for (int p = 0; p < 8; ++p) { acc[p] = __expf(acc[p] - mx[p]); sm[p] = acc[p]; }
#pragma unroll
  for (int s = 1; s < 64; s <<= 1) {
#pragma unroll
    for (int p = 0; p < 8; ++p) sm[p] += __shfl_xor(sm[p], s);
  }

  // tanh(softmax)*2 and store (lane = cout; per-p uniform validity)
  float* op = out + ((size_t)(b * 64 + lane) * 63 + oh) * 63 + 2 * seg + CP;
#pragma unroll
  for (int p = 0; p < 8; ++p) {
    if (p < npx) {
      float sv = acc[p] / sm[p];
      float e2 = __expf(2.0f * sv);                 // 2*tanh(s) = 2 - 4/(e^2s+1)
      op[2 * p] = 2.0f - 4.0f / (e2 + 1.0f);
    }
  }
}

extern "C" __global__ __launch_bounds__(256, 4) void k_main(
    const float* __restrict__ ws, float* __restrict__ out) {
  const int tid  = threadIdx.x;
  const int lane = tid & 63;
  // wave id: (((b*63 + oh)*2 + cp)*4 + q); 4 waves of a block share (b,oh,cp)
  const int wid = blockIdx.x * 4 + __builtin_amdgcn_readfirstlane(tid >> 6);
  const int q  = wid & 3;
  const int cp = (wid >> 2) & 1;
  const int t2 = wid >> 3;                          // b*63 + oh
  const int oh = t2 % 63;
  const int b  = t2 / 63;
  const int rp = oh & 1;
  if      (rp == 0 && cp == 0) wave_body<0, 0>(ws, out, b, oh, q, lane);
  else if (rp == 0 && cp == 1) wave_body<0, 1>(ws, out, b, oh, q, lane);
  else if (rp == 1 && cp == 0) wave_body<1, 0>(ws, out, b, oh, q, lane);
  else                         wave_body<1, 1>(ws, out, b, oh, q, lane);
}

extern "C" void kernel_launch(void* const* d_in, const int* in_sizes, int n_in,
                              void* d_out, int out_size, void* d_ws,
                              size_t ws_size, hipStream_t stream) {
  const float* x  = (const float*)d_in[0];
  const float* w  = (const float*)d_in[1];
  const float* cb = (const float*)d_in[2];
  const float* bs = (const float*)d_in[3];
  float* ws  = (float*)d_ws;
  float* out = (float*)d_out;

  hipLaunchKernelGGL(k_prep, dim3(520),  dim3(256), 0, stream, x, w, cb, bs, ws);
  hipLaunchKernelGGL(k_main, dim3(1008), dim3(256), 0, stream, ws, out);
}

// Round 5
// 108.762 us; speedup vs baseline: 1.1450x; 1.1450x over previous
//
#include <hip/hip_runtime.h>
#include <cstddef>

// B=8, Cin=32, D=16, H=W=32 -> ConvTranspose3d(32->64, k=3, s=2, p=1)
// -> mean over depth (D'=31) -> +bias -> softmax over C=64 -> tanh*2.
// Output (8, 64, 1, 63, 63) fp32.
//
// Depth-mean folds into weights: A0 = S - x[0], A1 = S, A2 = S - x[15]
// (S = sum_d x), m = cb + sum_kd Tconv2d(A_kd, w/31).
// Parity classes (oh&1, ow&1): taps/cin = 3 (EE), 6 (EO/OE), 12 (OO).
//
// ROUND-5 PRINCIPLE: no scalar-path streaming. Rounds 1-4 all streamed a bulk
// operand via wave-uniform s_load (scalar K$ has ~no miss pipelining ->
// serialized ~300cy/miss -> 46-106us with every pipe idle). Now:
//   - weights: transposed table [tap][cin][cout] -> lane-consecutive 256B
//     global_load_dword, register double-buffered (prefetch ci+1).
//   - A rows: packed per (b,ih) as [kd][cin][w] (12KB contiguous), staged to
//     LDS with float4 vector copies, read as uniform LDS broadcasts.
// Block = (b, oh): 8 waves; wave = (ow-parity, 8-pixel group); lanes = couts;
// acc[8]; in-wave 64-lane butterfly softmax; no cross-wave coupling.

namespace {
constexpr int OFF_EE = 0;                          // T=3  [tap][cin][cout]
constexpr int OFF_EO = 32 * 64 * 3;                // T=6
constexpr int OFF_OE = OFF_EO + 32 * 64 * 6;       // T=6
constexpr int OFF_OO = OFF_OE + 32 * 64 * 6;       // T=12
constexpr int OFF_CB = OFF_OO + 32 * 64 * 12;      // cb[64]
constexpr int OFF_A  = OFF_CB + 64;                // A'[b][ih][kd][cin][w]
}

// ---------------- prep: weight transform (+bias) AND depth reduce ----------
extern "C" __global__ __launch_bounds__(256) void k_prep(
    const float* __restrict__ x, const float* __restrict__ w,
    const float* __restrict__ conv_bias, const float* __restrict__ bias,
    float* __restrict__ ws) {
  const int bid = blockIdx.x;
  const int tid = threadIdx.x;
  if (bid < 8) {
    int t = bid * 256 + tid;                       // cin*64+cout over 2048
    if (t < 64) ws[OFF_CB + t] = conv_bias[t] + bias[t];
    if (t >= 32 * 64) return;
    const int cin = t >> 6, cout = t & 63;
    const float s = 1.0f / 31.0f;
    const float* src = w + t * 27;                 // (Cin, Cout, 3,3,3)
    float wv[27];
#pragma unroll
    for (int i = 0; i < 27; ++i) wv[i] = src[i] * s;
    // transposed tables: ws[toff + (tap*32 + cin)*64 + cout]
#pragma unroll
    for (int kd = 0; kd < 3; ++kd) {
      ws[OFF_EE + ((kd)*32 + cin) * 64 + cout]           = wv[kd * 9 + 4]; // (1,1)
      ws[OFF_EO + ((kd * 2 + 0) * 32 + cin) * 64 + cout] = wv[kd * 9 + 3]; // (1,0) a[j+1]
      ws[OFF_EO + ((kd * 2 + 1) * 32 + cin) * 64 + cout] = wv[kd * 9 + 5]; // (1,2) a[j]
      ws[OFF_OE + ((kd * 2 + 0) * 32 + cin) * 64 + cout] = wv[kd * 9 + 1]; // (0,1) rowA
      ws[OFF_OE + ((kd * 2 + 1) * 32 + cin) * 64 + cout] = wv[kd * 9 + 7]; // (2,1) rowB
      ws[OFF_OO + ((kd * 4 + 0) * 32 + cin) * 64 + cout] = wv[kd * 9 + 0]; // rA a[j+1]
      ws[OFF_OO + ((kd * 4 + 1) * 32 + cin) * 64 + cout] = wv[kd * 9 + 2]; // rA a[j]
      ws[OFF_OO + ((kd * 4 + 2) * 32 + cin) * 64 + cout] = wv[kd * 9 + 6]; // rB a[j+1]
      ws[OFF_OO + ((kd * 4 + 3) * 32 + cin) * 64 + cout] = wv[kd * 9 + 8]; // rB a[j]
    }
  } else {
    // depth reduce, d-split across lane halves: 131072 threads
    int t = (bid - 8) * 256 + tid;
    int g = t >> 6;
    int lane = t & 63;
    int dh = lane >> 5;
    int o = g * 32 + (lane & 31);                  // float4 work index
    int bc = o >> 8;                               // b*32+cin
    int c4 = o & 255;                              // ih*8 + w4
    int b = bc >> 5, cin = bc & 31;
    int ih = c4 >> 3, w4 = c4 & 7;
    const float4* xp = (const float4*)x + (size_t)bc * 4096 + c4;
    float4 vv[8];
#pragma unroll
    for (int j = 0; j < 8; ++j) vv[j] = xp[(dh * 8 + j) * 256];
    float sx = 0.f, sy = 0.f, sz = 0.f, sw = 0.f;
#pragma unroll
    for (int j = 0; j < 8; ++j) { sx += vv[j].x; sy += vv[j].y; sz += vv[j].z; sw += vv[j].w; }
    float fx = sx + __shfl_xor(sx, 32);
    float fy = sy + __shfl_xor(sy, 32);
    float fz = sz + __shfl_xor(sz, 32);
    float fw = sw + __shfl_xor(sw, 32);
    // A'[b][ih][kd][cin][w]: f4 dst = ((b*32+ih)*3+kd)*256 + cin*8 + w4
    float4* Af = (float4*)(ws + OFF_A);
    size_t base = ((size_t)(b * 32 + ih) * 3) * 256 + cin * 8 + w4;
    if (dh == 0) {
      float4 a0; a0.x = fx - vv[0].x; a0.y = fy - vv[0].y; a0.z = fz - vv[0].z; a0.w = fw - vv[0].w;
      Af[base] = a0;                               // kd=0 (drops d=0)
      float4 a1; a1.x = fx; a1.y = fy; a1.z = fz; a1.w = fw;
      Af[base + 256] = a1;                         // kd=1
    } else {
      float4 a2; a2.x = fx - vv[7].x; a2.y = fy - vv[7].y; a2.z = fz - vv[7].z; a2.w = fw - vv[7].w;
      Af[base + 512] = a2;                         // kd=2 (drops d=15)
    }
  }
}

// ---------------- main ----------------
template <int RP, int CP>
__device__ __forceinline__ void conv_row(const float* __restrict__ ws,
                                         float* __restrict__ out,
                                         const float (&alds)[2][3][32][32],
                                         int b, int oh, int widx, int lane) {
  constexpr int T = 3 * (RP + 1) * (CP + 1);
  constexpr int toff = RP ? (CP ? OFF_OO : OFF_OE) : (CP ? OFF_EO : OFF_EE);
  const int j0 = widx * 8;
  const int npx = (CP == 1 && widx == 3) ? 7 : 8;
  const float* wt = ws + toff;

  float wcur[T], wnxt[T];
#pragma unroll
  for (int t = 0; t < T; ++t) wcur[t] = wt[(t * 32) * 64 + lane];

  float acc[8];
#pragma unroll
  for (int p = 0; p < 8; ++p) acc[p] = 0.f;

  for (int ci = 0; ci < 32; ++ci) {
    if (ci < 31) {                                  // prefetch next cin
#pragma unroll
      for (int t = 0; t < T; ++t) wnxt[t] = wt[(t * 32 + ci + 1) * 64 + lane];
    }
#pragma unroll
    for (int kd = 0; kd < 3; ++kd) {
      if constexpr (CP == 0) {
        float a0[8];
#pragma unroll
        for (int p = 0; p < 8; ++p) a0[p] = alds[0][kd][ci][j0 + p];
        if constexpr (RP == 0) {
          const float w1 = wcur[kd];
#pragma unroll
          for (int p = 0; p < 8; ++p) acc[p] = fmaf(a0[p], w1, acc[p]);
        } else {
          float b0[8];
#pragma unroll
          for (int p = 0; p < 8; ++p) b0[p] = alds[1][kd][ci][j0 + p];
          const float wa = wcur[kd * 2], wb = wcur[kd * 2 + 1];
#pragma unroll
          for (int p = 0; p < 8; ++p) {
            acc[p] = fmaf(a0[p], wa, acc[p]);
            acc[p] = fmaf(b0[p], wb, acc[p]);
          }
        }
      } else {
        float av[9];
#pragma unroll
        for (int k = 0; k < 8; ++k) av[k] = alds[0][kd][ci][j0 + k];
        av[8] = (j0 + 8 < 32) ? alds[0][kd][ci][(j0 + 8) & 31] : 0.f;
        if constexpr (RP == 0) {
          const float w0 = wcur[kd * 2], w2 = wcur[kd * 2 + 1];
#pragma unroll
          for (int p = 0; p < 8; ++p) {
            acc[p] = fmaf(av[p + 1], w0, acc[p]);
            acc[p] = fmaf(av[p],     w2, acc[p]);
          }
        } else {
          float bv[9];
#pragma unroll
          for (int k = 0; k < 8; ++k) bv[k] = alds[1][kd][ci][j0 + k];
          bv[8] = (j0 + 8 < 32) ? alds[1][kd][ci][(j0 + 8) & 31] : 0.f;
          const float w00 = wcur[kd * 4 + 0], w02 = wcur[kd * 4 + 1];
          const float w20 = wcur[kd * 4 + 2], w22 = wcur[kd * 4 + 3];
#pragma unroll
          for (int p = 0; p < 8; ++p) {
            acc[p] = fmaf(av[p + 1], w00, acc[p]);
            acc[p] = fmaf(av[p],     w02, acc[p]);
            acc[p] = fmaf(bv[p + 1], w20, acc[p]);
            acc[p] = fmaf(bv[p],     w22, acc[p]);
          }
        }
      }
    }
    if (ci < 31) {
#pragma unroll
      for (int t = 0; t < T; ++t) wcur[t] = wnxt[t];
    }
  }

  // bias + in-wave softmax over lanes (=couts), 8 interleaved chains
  const float cbv = ws[OFF_CB + lane];
  float mx[8], sm[8];
#pragma unroll
  for (int p = 0; p < 8; ++p) { acc[p] += cbv; mx[p] = acc[p]; }
#pragma unroll
  for (int s = 1; s < 64; s <<= 1) {
#pragma unroll
    for (int p = 0; p < 8; ++p) mx[p] = fmaxf(mx[p], __shfl_xor(mx[p], s));
  }
#pragma unroll
  for (int p = 0; p < 8; ++p) { acc[p] = __expf(acc[p] - mx[p]); sm[p] = acc[p]; }
#pragma unroll
  for (int s = 1; s < 64; s <<= 1) {
#pragma unroll
    for (int p = 0; p < 8; ++p) sm[p] += __shfl_xor(sm[p], s);
  }
  float* op = out + ((size_t)(b * 64 + lane) * 63 + oh) * 63;
#pragma unroll
  for (int p = 0; p < 8; ++p) {
    if (p < npx) {
      float sv = acc[p] / sm[p];
      float e2 = __expf(2.0f * sv);                 // 2*tanh(s) = 2 - 4/(e^2s+1)
      op[2 * (j0 + p) + CP] = 2.0f - 4.0f / (e2 + 1.0f);
    }
  }
}

extern "C" __global__ __launch_bounds__(512, 4) void k_main(
    const float* __restrict__ ws, float* __restrict__ out) {
  __shared__ float alds[2][3][32][32];              // 24.6 KB
  const int oh = blockIdx.x;                        // 0..62
  const int b  = blockIdx.y;                        // 0..7
  const int rp = oh & 1;
  const int tid = threadIdx.x;

  // stage A rows (vector float4 path, lane-linear LDS writes)
  const int ihA = rp ? (oh + 1) >> 1 : oh >> 1;
  const float4* Af = (const float4*)(ws + OFF_A);
  {
    const float4* sA = Af + (size_t)((b * 32 + ihA) * 3) * 256;
    float4* dA = (float4*)&alds[0][0][0][0];
    for (int i = tid; i < 768; i += 512) dA[i] = sA[i];
  }
  if (rp) {
    const int ihB = (oh - 1) >> 1;
    const float4* sB = Af + (size_t)((b * 32 + ihB) * 3) * 256;
    float4* dB = (float4*)&alds[1][0][0][0];
    for (int i = tid; i < 768; i += 512) dB[i] = sB[i];
  }
  __syncthreads();

  const int wid  = __builtin_amdgcn_readfirstlane(tid >> 6);  // 0..7
  const int lane = tid & 63;                        // cout
  const int cp   = wid >> 2;                        // ow parity (wave-uniform)
  const int widx = wid & 3;                         // 8-pixel group
  if (rp == 0) {
    if (cp == 0) conv_row<0, 0>(ws, out, alds, b, oh, widx, lane);
    else         conv_row<0, 1>(ws, out, alds, b, oh, widx, lane);
  } else {
    if (cp == 0) conv_row<1, 0>(ws, out, alds, b, oh, widx, lane);
    else         conv_row<1, 1>(ws, out, alds, b, oh, widx, lane);
  }
}

extern "C" void kernel_launch(void* const* d_in, const int* in_sizes, int n_in,
                              void* d_out, int out_size, void* d_ws,
                              size_t ws_size, hipStream_t stream) {
  const float* x  = (const float*)d_in[0];
  const float* w  = (const float*)d_in[1];
  const float* cb = (const float*)d_in[2];
  const float* bs = (const float*)d_in[3];
  float* ws  = (float*)d_ws;
  float* out = (float*)d_out;

  hipLaunchKernelGGL(k_prep, dim3(520), dim3(256), 0, stream, x, w, cb, bs, ws);
  hipLaunchKernelGGL(k_main, dim3(63, 8), dim3(512), 0, stream, ws, out);
}